// Round 1
// baseline (890.397 us; speedup 1.0000x reference)
//
#include <hip/hip_runtime.h>
#include <hip/hip_bf16.h>

// Problem constants (fixed by reference): B=64, C=32, V=1024, L=12, ORDER=2
// Decomposition:
//   adp = softmax(relu(nv1@nv2), axis=1)
//   Bt_cat[6][1024][1024] bf16:  slice k, row w, col v = G_k[v][w]
//     G = {A1, A1^2, A2, A2^2, adp, adp^2}
//   xT bf16 rows m=(b*12+l)*32+c, cols v   (row-major K=1024)
//   R[m,(k,w)] = sum_v xT[m,v]*G_k[v,w]  stored in layout [b][l][k][c][w] bf16
//   out[b,o,w,l] = bias[o] + sum_c W[o,c]*x[b,c,w,l] + sum_{k,c} W[o,32(k+1)+c]*R_k[b,c,w,l]

typedef __attribute__((ext_vector_type(8))) short short8;
typedef __attribute__((ext_vector_type(4))) float floatx4;

#define V_DIM 1024
#define L_DIM 12
#define B_DIM 64
#define C_DIM 32

// ---------------- adp: relu + row softmax --------------------------------
__global__ __launch_bounds__(128) void adp_kernel(
    const float* __restrict__ nv1, const float* __restrict__ nv2,
    float* __restrict__ adp) {
  const int v = blockIdx.x, tid = threadIdx.x;
  float n1[10];
#pragma unroll
  for (int i = 0; i < 10; ++i) n1[i] = nv1[v * 10 + i];
  __shared__ float red[128];
  float e[8];
  float lmax = -1e30f;
#pragma unroll
  for (int j = 0; j < 8; ++j) {
    int w = tid + j * 128;
    float s = 0.f;
#pragma unroll
    for (int i = 0; i < 10; ++i) s += n1[i] * nv2[i * V_DIM + w];
    s = fmaxf(s, 0.f);
    e[j] = s;
    lmax = fmaxf(lmax, s);
  }
  red[tid] = lmax; __syncthreads();
  for (int s = 64; s > 0; s >>= 1) {
    if (tid < s) red[tid] = fmaxf(red[tid], red[tid + s]);
    __syncthreads();
  }
  float mx = red[0]; __syncthreads();
  float lsum = 0.f;
#pragma unroll
  for (int j = 0; j < 8; ++j) { e[j] = __expf(e[j] - mx); lsum += e[j]; }
  red[tid] = lsum; __syncthreads();
  for (int s = 64; s > 0; s >>= 1) {
    if (tid < s) red[tid] += red[tid + s];
    __syncthreads();
  }
  float inv = 1.f / red[0];
#pragma unroll
  for (int j = 0; j < 8; ++j) adp[(size_t)v * V_DIM + tid + j * 128] = e[j] * inv;
}

// ------------- cast supports to bf16: straight + transposed ---------------
__global__ __launch_bounds__(256) void cast_transpose(
    const float* __restrict__ A1, const float* __restrict__ A2,
    const float* __restrict__ adp, __hip_bfloat16* __restrict__ As,
    __hip_bfloat16* __restrict__ BtCat) {
  const int z = blockIdx.z;
  const float* src = (z == 0) ? A1 : (z == 1) ? A2 : adp;
  __hip_bfloat16* sdst = As + (size_t)z * V_DIM * V_DIM;
  __hip_bfloat16* tdst = BtCat + (size_t)(2 * z) * V_DIM * V_DIM;
  __shared__ float tile[64][65];
  const int v0 = blockIdx.y * 64, w0 = blockIdx.x * 64;
  const int tc = threadIdx.x & 15, tr = threadIdx.x >> 4;
#pragma unroll
  for (int i = 0; i < 4; ++i) {
    int r = tr + i * 16;
    float4 val = *(const float4*)(src + (size_t)(v0 + r) * V_DIM + w0 + tc * 4);
    tile[r][tc * 4 + 0] = val.x; tile[r][tc * 4 + 1] = val.y;
    tile[r][tc * 4 + 2] = val.z; tile[r][tc * 4 + 3] = val.w;
    __hip_bfloat16* sp = sdst + (size_t)(v0 + r) * V_DIM + w0 + tc * 4;
    sp[0] = __float2bfloat16(val.x); sp[1] = __float2bfloat16(val.y);
    sp[2] = __float2bfloat16(val.z); sp[3] = __float2bfloat16(val.w);
  }
  __syncthreads();
#pragma unroll
  for (int i = 0; i < 4; ++i) {
    int r = tr + i * 16;  // output row = w0 + r
    __hip_bfloat16* tp = tdst + (size_t)(w0 + r) * V_DIM + v0 + tc * 4;
#pragma unroll
    for (int j = 0; j < 4; ++j) tp[j] = __float2bfloat16(tile[tc * 4 + j][r]);
  }
}

// ------------- x [B,C,V,L] fp32 -> xT bf16 rows (b*12+l)*32+c -------------
__global__ __launch_bounds__(256) void transpose_x_k(
    const float* __restrict__ x, __hip_bfloat16* __restrict__ xT) {
  const int bc = blockIdx.x;         // b*32+c
  const int b = bc >> 5, c = bc & 31;
  __shared__ __align__(16) __hip_bfloat16 tile[V_DIM * L_DIM];  // idx v*12+l
  const float4* src = (const float4*)(x + (size_t)bc * (V_DIM * L_DIM));
#pragma unroll
  for (int i = 0; i < 12; ++i) {
    int idx = threadIdx.x + i * 256;  // 3072 float4
    float4 v = src[idx];
    int e = idx * 4;
    tile[e + 0] = __float2bfloat16(v.x); tile[e + 1] = __float2bfloat16(v.y);
    tile[e + 2] = __float2bfloat16(v.z); tile[e + 3] = __float2bfloat16(v.w);
  }
  __syncthreads();
  for (int l = 0; l < L_DIM; ++l) {
    __hip_bfloat16* dst = xT + ((size_t)(b * L_DIM + l) * C_DIM + c) * V_DIM;
    for (int v = threadIdx.x; v < V_DIM; v += 256) dst[v] = tile[v * L_DIM + l];
  }
}

// ---------------- MFMA GEMM: C = A * Bt^T over K --------------------------
// A [M,K] bf16 row-major, Bt [N,K] bf16 row-major.
// MODE 0: C row-major bf16 [M,N]. MODE 1: R-layout scatter (see top).
__device__ __forceinline__ void gll16(const __hip_bfloat16* g, __hip_bfloat16* l) {
  __builtin_amdgcn_global_load_lds(
      (const __attribute__((address_space(1))) void*)g,
      (__attribute__((address_space(3))) void*)l, 16, 0, 0);
}

template <int MODE>
__global__ __launch_bounds__(256) void gemm_bt(
    const __hip_bfloat16* __restrict__ Abase,
    const __hip_bfloat16* __restrict__ Btbase,
    __hip_bfloat16* __restrict__ Cbase, int M, int N, int K,
    long long aStride, long long bStride, long long cStride) {
  const __hip_bfloat16* A = Abase + (size_t)blockIdx.z * aStride;
  const __hip_bfloat16* Bt = Btbase + (size_t)blockIdx.z * bStride;
  __hip_bfloat16* C = Cbase + (size_t)blockIdx.z * cStride;
  __shared__ __align__(16) __hip_bfloat16 lA[128 * 64];
  __shared__ __align__(16) __hip_bfloat16 lB[128 * 64];
  const int tid = threadIdx.x;
  const int wv = tid >> 6, lane = tid & 63;
  const int wm = wv >> 1, wn = wv & 1;
  const int m0 = blockIdx.y * 128, n0 = blockIdx.x * 128;
  const int lrow = lane >> 3, lcol = lane & 7;  // staging: 8 rows / wave-instr
  const int fr = lane & 15, quad = lane >> 4;   // fragment coords

  floatx4 acc[4][4];
#pragma unroll
  for (int i = 0; i < 4; ++i)
#pragma unroll
    for (int j = 0; j < 4; ++j) acc[i][j] = (floatx4){0.f, 0.f, 0.f, 0.f};

  for (int kt = 0; kt < K; kt += 64) {
    __syncthreads();  // previous tile fully consumed
#pragma unroll
    for (int i = 0; i < 4; ++i) {
      int r0 = (wv * 4 + i) * 8;
      gll16(A + (size_t)(m0 + r0 + lrow) * K + kt + lcol * 8, &lA[r0 * 64]);
      gll16(Bt + (size_t)(n0 + r0 + lrow) * K + kt + lcol * 8, &lB[r0 * 64]);
    }
    __syncthreads();  // drains vmcnt(0): staged data visible
#pragma unroll
    for (int ks = 0; ks < 2; ++ks) {
      short8 af[4], bfr[4];
#pragma unroll
      for (int t = 0; t < 4; ++t) {
        af[t] = *(const short8*)&lA[(wm * 64 + t * 16 + fr) * 64 + ks * 32 + quad * 8];
        bfr[t] = *(const short8*)&lB[(wn * 64 + t * 16 + fr) * 64 + ks * 32 + quad * 8];
      }
#pragma unroll
      for (int i = 0; i < 4; ++i)
#pragma unroll
        for (int j = 0; j < 4; ++j)
          acc[i][j] = __builtin_amdgcn_mfma_f32_16x16x32_bf16(af[i], bfr[j], acc[i][j], 0, 0, 0);
    }
  }
  // epilogue: C/D layout col=lane&15, row=quad*4+reg (m89-verified)
#pragma unroll
  for (int i = 0; i < 4; ++i) {
#pragma unroll
    for (int j = 0; j < 4; ++j) {
      int mb = m0 + wm * 64 + i * 16 + quad * 4;
      int n = n0 + wn * 64 + j * 16 + fr;
#pragma unroll
      for (int r = 0; r < 4; ++r) {
        int m = mb + r;
        float val = acc[i][j][r];
        size_t idx;
        if (MODE == 0) {
          idx = (size_t)m * N + n;
        } else {
          int c = m & 31, bl = m >> 5, k = n >> 10, w = n & 1023;
          idx = (((size_t)bl * 6 + k) * 32 + c) * 1024 + w;
        }
        C[idx] = __float2bfloat16(val);
      }
    }
  }
}

// ---------------- mix: out = W * concat(x, hops) + b ----------------------
__global__ __launch_bounds__(256) void mix_kernel(
    const __hip_bfloat16* __restrict__ R, const __hip_bfloat16* __restrict__ xT,
    const float* __restrict__ W, const float* __restrict__ bias,
    float* __restrict__ out) {
  const int b = blockIdx.y, wt = blockIdx.x;
  const int tid = threadIdx.x;
  __shared__ __align__(16) __hip_bfloat16 tile[L_DIM * C_DIM * 64];  // [l][c][w64]
  __shared__ float Wl[7 * 32 * 32];  // Wl[(p*32+c)*32+o] = W[o][p*32+c]
  for (int i = tid; i < 7168; i += 256) {
    int o = i / 224, cc = i - o * 224;
    Wl[cc * 32 + o] = W[i];
  }
  float acc[3][32];
#pragma unroll
  for (int pt = 0; pt < 3; ++pt)
#pragma unroll
    for (int o = 0; o < 32; ++o) acc[pt][o] = bias[o];
  int wloc[3], ll[3];
#pragma unroll
  for (int pt = 0; pt < 3; ++pt) {
    int wl = tid + pt * 256;
    wloc[pt] = wl / 12;
    ll[pt] = wl - wloc[pt] * 12;
  }
  const int w0 = wt * 64;
  for (int k = 0; k < 7; ++k) {
    __syncthreads();
    const __hip_bfloat16* srcp = (k < 6) ? R : xT;
    const int rps = (k < 6) ? 192 : 32;  // rows per (b,l)
    const int ko = (k < 6) ? k * 32 : 0;
#pragma unroll
    for (int i = 0; i < 24; ++i) {       // 6144 ushort4 chunks
      int q = tid + i * 256;
      int rr = q >> 4, ci = q & 15;      // rr = l*32+c
      int l = rr >> 5, c = rr & 31;
      size_t rowg = (size_t)(b * L_DIM + l) * rps + ko + c;
      *(ushort4*)&tile[rr * 64 + ci * 4] =
          *(const ushort4*)&srcp[rowg * V_DIM + w0 + ci * 4];
    }
    __syncthreads();
    const float* Wp = &Wl[((k < 6) ? (k + 1) : 0) * 1024];
    const int base0 = ll[0] * 2048 + wloc[0];
    const int base1 = ll[1] * 2048 + wloc[1];
    const int base2 = ll[2] * 2048 + wloc[2];
#pragma unroll 8
    for (int c = 0; c < 32; ++c) {
      float v0 = __bfloat162float(tile[base0 + c * 64]);
      float v1 = __bfloat162float(tile[base1 + c * 64]);
      float v2 = __bfloat162float(tile[base2 + c * 64]);
#pragma unroll
      for (int o = 0; o < 32; ++o) {
        float wv = Wp[c * 32 + o];
        acc[0][o] += wv * v0;
        acc[1][o] += wv * v1;
        acc[2][o] += wv * v2;
      }
    }
  }
  const size_t obase = (size_t)b * (32 * V_DIM * L_DIM) + (size_t)w0 * L_DIM;
#pragma unroll
  for (int o = 0; o < 32; ++o) {
    size_t base = obase + (size_t)o * (V_DIM * L_DIM);
    out[base + tid] = acc[0][o];
    out[base + tid + 256] = acc[1][o];
    out[base + tid + 512] = acc[2][o];
  }
}

// --------------------------- launcher ------------------------------------
extern "C" void kernel_launch(void* const* d_in, const int* in_sizes, int n_in,
                              void* d_out, int out_size, void* d_ws,
                              size_t ws_size, hipStream_t stream) {
  const float* x = (const float*)d_in[0];
  const float* A1 = (const float*)d_in[1];
  const float* A2 = (const float*)d_in[2];
  const float* nv1 = (const float*)d_in[3];
  const float* nv2 = (const float*)d_in[4];
  const float* W = (const float*)d_in[5];
  const float* bias = (const float*)d_in[6];
  float* out = (float*)d_out;

  char* ws = (char*)d_ws;
  // ws layout (bytes): R 301,989,888 | xT 50,331,648 | BtCat 12,582,912 |
  //                    As 6,291,456 | adp 4,194,304   => total ~375.4 MB
  __hip_bfloat16* R = (__hip_bfloat16*)(ws + 0);
  __hip_bfloat16* xT = (__hip_bfloat16*)(ws + 301989888ull);
  __hip_bfloat16* BtCat = (__hip_bfloat16*)(ws + 352321536ull);
  __hip_bfloat16* As = (__hip_bfloat16*)(ws + 364904448ull);
  float* adp = (float*)(ws + 371195904ull);

  // 1. adaptive adjacency
  adp_kernel<<<dim3(1024), dim3(128), 0, stream>>>(nv1, nv2, adp);
  // 2. bf16 casts: straight (As) + transposed (BtCat slices 0,2,4)
  cast_transpose<<<dim3(16, 16, 3), dim3(256), 0, stream>>>(A1, A2, adp, As, BtCat);
  // 3. squares: BtCat slice 2z+1 = (a^2)^T = At @ As^T   (M=N=K=1024)
  gemm_bt<0><<<dim3(8, 8, 3), dim3(256), 0, stream>>>(
      BtCat, As, BtCat + 1048576ull, 1024, 1024, 1024,
      2097152ll, 1048576ll, 2097152ll);
  // 4. x -> xT bf16
  transpose_x_k<<<dim3(2048), dim3(256), 0, stream>>>(x, xT);
  // 5. main diffusion GEMM: R = xT @ BtCat^T  (M=24576, N=6144, K=1024)
  gemm_bt<1><<<dim3(48, 192, 1), dim3(256), 0, stream>>>(
      xT, BtCat, R, 24576, 6144, 1024, 0ll, 0ll, 0ll);
  // 6. channel mix + bias -> out
  mix_kernel<<<dim3(16, 64), dim3(256), 0, stream>>>(R, xT, W, bias, out);
}

// Round 2
// 797.352 us; speedup vs baseline: 1.1167x; 1.1167x over previous
//
#include <hip/hip_runtime.h>
#include <hip/hip_bf16.h>

// Problem constants (fixed by reference): B=64, C=32, V=1024, L=12, ORDER=2
// Decomposition:
//   adp = softmax(relu(nv1@nv2), axis=1)
//   Bt_cat[6][1024][1024] bf16:  slice k, row w, col v = G_k[v][w]
//     G = {A1, A1^2, A2, A2^2, adp, adp^2}
//   xT bf16 rows m=(b*12+l)*32+c, cols v   (row-major K=1024)
//   R[m,(k,w)] = sum_v xT[m,v]*G_k[v,w]  stored in layout [b][l][k][c][w] bf16
//   out[b,o,w,l] = bias[o] + sum_c W[o,c]*x[b,c,w,l] + sum_{k,c} W[o,32(k+1)+c]*R_k[b,c,w,l]
//
// R1 change: XOR bank-swizzle on the GEMM LDS tiles. LDS slot (row, chunk c)
// holds global K-chunk (c ^ (row&7)); staging permutes per-lane global
// addresses (global_load_lds lane->slot map is fixed, global side is free).
// Kills the 16-way column-read conflicts (SQ_LDS_BANK_CONFLICT was 1.13e8).

typedef __attribute__((ext_vector_type(8))) short short8;
typedef __attribute__((ext_vector_type(4))) float floatx4;

#define V_DIM 1024
#define L_DIM 12
#define B_DIM 64
#define C_DIM 32

// ---------------- adp: relu + row softmax --------------------------------
__global__ __launch_bounds__(128) void adp_kernel(
    const float* __restrict__ nv1, const float* __restrict__ nv2,
    float* __restrict__ adp) {
  const int v = blockIdx.x, tid = threadIdx.x;
  float n1[10];
#pragma unroll
  for (int i = 0; i < 10; ++i) n1[i] = nv1[v * 10 + i];
  __shared__ float red[128];
  float e[8];
  float lmax = -1e30f;
#pragma unroll
  for (int j = 0; j < 8; ++j) {
    int w = tid + j * 128;
    float s = 0.f;
#pragma unroll
    for (int i = 0; i < 10; ++i) s += n1[i] * nv2[i * V_DIM + w];
    s = fmaxf(s, 0.f);
    e[j] = s;
    lmax = fmaxf(lmax, s);
  }
  red[tid] = lmax; __syncthreads();
  for (int s = 64; s > 0; s >>= 1) {
    if (tid < s) red[tid] = fmaxf(red[tid], red[tid + s]);
    __syncthreads();
  }
  float mx = red[0]; __syncthreads();
  float lsum = 0.f;
#pragma unroll
  for (int j = 0; j < 8; ++j) { e[j] = __expf(e[j] - mx); lsum += e[j]; }
  red[tid] = lsum; __syncthreads();
  for (int s = 64; s > 0; s >>= 1) {
    if (tid < s) red[tid] += red[tid + s];
    __syncthreads();
  }
  float inv = 1.f / red[0];
#pragma unroll
  for (int j = 0; j < 8; ++j) adp[(size_t)v * V_DIM + tid + j * 128] = e[j] * inv;
}

// ------------- cast supports to bf16: straight + transposed ---------------
__global__ __launch_bounds__(256) void cast_transpose(
    const float* __restrict__ A1, const float* __restrict__ A2,
    const float* __restrict__ adp, __hip_bfloat16* __restrict__ As,
    __hip_bfloat16* __restrict__ BtCat) {
  const int z = blockIdx.z;
  const float* src = (z == 0) ? A1 : (z == 1) ? A2 : adp;
  __hip_bfloat16* sdst = As + (size_t)z * V_DIM * V_DIM;
  __hip_bfloat16* tdst = BtCat + (size_t)(2 * z) * V_DIM * V_DIM;
  __shared__ float tile[64][65];
  const int v0 = blockIdx.y * 64, w0 = blockIdx.x * 64;
  const int tc = threadIdx.x & 15, tr = threadIdx.x >> 4;
#pragma unroll
  for (int i = 0; i < 4; ++i) {
    int r = tr + i * 16;
    float4 val = *(const float4*)(src + (size_t)(v0 + r) * V_DIM + w0 + tc * 4);
    tile[r][tc * 4 + 0] = val.x; tile[r][tc * 4 + 1] = val.y;
    tile[r][tc * 4 + 2] = val.z; tile[r][tc * 4 + 3] = val.w;
    __hip_bfloat16* sp = sdst + (size_t)(v0 + r) * V_DIM + w0 + tc * 4;
    sp[0] = __float2bfloat16(val.x); sp[1] = __float2bfloat16(val.y);
    sp[2] = __float2bfloat16(val.z); sp[3] = __float2bfloat16(val.w);
  }
  __syncthreads();
#pragma unroll
  for (int i = 0; i < 4; ++i) {
    int r = tr + i * 16;  // output row = w0 + r
    __hip_bfloat16* tp = tdst + (size_t)(w0 + r) * V_DIM + v0 + tc * 4;
#pragma unroll
    for (int j = 0; j < 4; ++j) tp[j] = __float2bfloat16(tile[tc * 4 + j][r]);
  }
}

// ------------- x [B,C,V,L] fp32 -> xT bf16 rows (b*12+l)*32+c -------------
__global__ __launch_bounds__(256) void transpose_x_k(
    const float* __restrict__ x, __hip_bfloat16* __restrict__ xT) {
  const int bc = blockIdx.x;         // b*32+c
  const int b = bc >> 5, c = bc & 31;
  __shared__ __align__(16) __hip_bfloat16 tile[V_DIM * L_DIM];  // idx v*12+l
  const float4* src = (const float4*)(x + (size_t)bc * (V_DIM * L_DIM));
#pragma unroll
  for (int i = 0; i < 12; ++i) {
    int idx = threadIdx.x + i * 256;  // 3072 float4
    float4 v = src[idx];
    int e = idx * 4;
    tile[e + 0] = __float2bfloat16(v.x); tile[e + 1] = __float2bfloat16(v.y);
    tile[e + 2] = __float2bfloat16(v.z); tile[e + 3] = __float2bfloat16(v.w);
  }
  __syncthreads();
  for (int l = 0; l < L_DIM; ++l) {
    __hip_bfloat16* dst = xT + ((size_t)(b * L_DIM + l) * C_DIM + c) * V_DIM;
    for (int v = threadIdx.x; v < V_DIM; v += 256) dst[v] = tile[v * L_DIM + l];
  }
}

// ---------------- MFMA GEMM: C = A * Bt^T over K --------------------------
// A [M,K] bf16 row-major, Bt [N,K] bf16 row-major.
// MODE 0: C row-major bf16 [M,N]. MODE 1: R-layout scatter (see top).
__device__ __forceinline__ void gll16(const __hip_bfloat16* g, __hip_bfloat16* l) {
  __builtin_amdgcn_global_load_lds(
      (const __attribute__((address_space(1))) void*)g,
      (__attribute__((address_space(3))) void*)l, 16, 0, 0);
}

template <int MODE>
__global__ __launch_bounds__(256) void gemm_bt(
    const __hip_bfloat16* __restrict__ Abase,
    const __hip_bfloat16* __restrict__ Btbase,
    __hip_bfloat16* __restrict__ Cbase, int M, int N, int K,
    long long aStride, long long bStride, long long cStride) {
  const __hip_bfloat16* A = Abase + (size_t)blockIdx.z * aStride;
  const __hip_bfloat16* Bt = Btbase + (size_t)blockIdx.z * bStride;
  __hip_bfloat16* C = Cbase + (size_t)blockIdx.z * cStride;
  __shared__ __align__(16) __hip_bfloat16 lA[128 * 64];
  __shared__ __align__(16) __hip_bfloat16 lB[128 * 64];
  const int tid = threadIdx.x;
  const int wv = tid >> 6, lane = tid & 63;
  const int wm = wv >> 1, wn = wv & 1;
  const int m0 = blockIdx.y * 128, n0 = blockIdx.x * 128;
  const int lrow = lane >> 3, lcol = lane & 7;  // staging: 8 rows / wave-instr
  // XOR bank swizzle: LDS slot (row, c) holds global chunk (c ^ (row&7)).
  const int gcol = lcol ^ (lrow & 7);           // global chunk this lane stages
  const int fr = lane & 15, quad = lane >> 4;   // fragment coords
  const int sw = fr & 7;                        // read-side swizzle key

  floatx4 acc[4][4];
#pragma unroll
  for (int i = 0; i < 4; ++i)
#pragma unroll
    for (int j = 0; j < 4; ++j) acc[i][j] = (floatx4){0.f, 0.f, 0.f, 0.f};

  for (int kt = 0; kt < K; kt += 64) {
    __syncthreads();  // previous tile fully consumed
#pragma unroll
    for (int i = 0; i < 4; ++i) {
      int r0 = (wv * 4 + i) * 8;
      gll16(A + (size_t)(m0 + r0 + lrow) * K + kt + gcol * 8, &lA[r0 * 64]);
      gll16(Bt + (size_t)(n0 + r0 + lrow) * K + kt + gcol * 8, &lB[r0 * 64]);
    }
    __syncthreads();  // drains vmcnt(0): staged data visible
#pragma unroll
    for (int ks = 0; ks < 2; ++ks) {
      const int chunk = (ks * 4 + quad) ^ sw;   // swizzled K-chunk slot
      short8 af[4], bfr[4];
#pragma unroll
      for (int t = 0; t < 4; ++t) {
        af[t] = *(const short8*)&lA[(wm * 64 + t * 16 + fr) * 64 + chunk * 8];
        bfr[t] = *(const short8*)&lB[(wn * 64 + t * 16 + fr) * 64 + chunk * 8];
      }
#pragma unroll
      for (int i = 0; i < 4; ++i)
#pragma unroll
        for (int j = 0; j < 4; ++j)
          acc[i][j] = __builtin_amdgcn_mfma_f32_16x16x32_bf16(af[i], bfr[j], acc[i][j], 0, 0, 0);
    }
  }
  // epilogue: C/D layout col=lane&15, row=quad*4+reg (m89-verified)
#pragma unroll
  for (int i = 0; i < 4; ++i) {
#pragma unroll
    for (int j = 0; j < 4; ++j) {
      int mb = m0 + wm * 64 + i * 16 + quad * 4;
      int n = n0 + wn * 64 + j * 16 + fr;
#pragma unroll
      for (int r = 0; r < 4; ++r) {
        int m = mb + r;
        float val = acc[i][j][r];
        size_t idx;
        if (MODE == 0) {
          idx = (size_t)m * N + n;
        } else {
          int c = m & 31, bl = m >> 5, k = n >> 10, w = n & 1023;
          idx = (((size_t)bl * 6 + k) * 32 + c) * 1024 + w;
        }
        C[idx] = __float2bfloat16(val);
      }
    }
  }
}

// ---------------- mix: out = W * concat(x, hops) + b ----------------------
__global__ __launch_bounds__(256) void mix_kernel(
    const __hip_bfloat16* __restrict__ R, const __hip_bfloat16* __restrict__ xT,
    const float* __restrict__ W, const float* __restrict__ bias,
    float* __restrict__ out) {
  const int b = blockIdx.y, wt = blockIdx.x;
  const int tid = threadIdx.x;
  __shared__ __align__(16) __hip_bfloat16 tile[L_DIM * C_DIM * 64];  // [l][c][w64]
  __shared__ float Wl[7 * 32 * 32];  // Wl[(p*32+c)*32+o] = W[o][p*32+c]
  for (int i = tid; i < 7168; i += 256) {
    int o = i / 224, cc = i - o * 224;
    Wl[cc * 32 + o] = W[i];
  }
  float acc[3][32];
#pragma unroll
  for (int pt = 0; pt < 3; ++pt)
#pragma unroll
    for (int o = 0; o < 32; ++o) acc[pt][o] = bias[o];
  int wloc[3], ll[3];
#pragma unroll
  for (int pt = 0; pt < 3; ++pt) {
    int wl = tid + pt * 256;
    wloc[pt] = wl / 12;
    ll[pt] = wl - wloc[pt] * 12;
  }
  const int w0 = wt * 64;
  for (int k = 0; k < 7; ++k) {
    __syncthreads();
    const __hip_bfloat16* srcp = (k < 6) ? R : xT;
    const int rps = (k < 6) ? 192 : 32;  // rows per (b,l)
    const int ko = (k < 6) ? k * 32 : 0;
#pragma unroll
    for (int i = 0; i < 24; ++i) {       // 6144 ushort4 chunks
      int q = tid + i * 256;
      int rr = q >> 4, ci = q & 15;      // rr = l*32+c
      int l = rr >> 5, c = rr & 31;
      size_t rowg = (size_t)(b * L_DIM + l) * rps + ko + c;
      *(ushort4*)&tile[rr * 64 + ci * 4] =
          *(const ushort4*)&srcp[rowg * V_DIM + w0 + ci * 4];
    }
    __syncthreads();
    const float* Wp = &Wl[((k < 6) ? (k + 1) : 0) * 1024];
    const int base0 = ll[0] * 2048 + wloc[0];
    const int base1 = ll[1] * 2048 + wloc[1];
    const int base2 = ll[2] * 2048 + wloc[2];
#pragma unroll 8
    for (int c = 0; c < 32; ++c) {
      float v0 = __bfloat162float(tile[base0 + c * 64]);
      float v1 = __bfloat162float(tile[base1 + c * 64]);
      float v2 = __bfloat162float(tile[base2 + c * 64]);
#pragma unroll
      for (int o = 0; o < 32; ++o) {
        float wv = Wp[c * 32 + o];
        acc[0][o] += wv * v0;
        acc[1][o] += wv * v1;
        acc[2][o] += wv * v2;
      }
    }
  }
  const size_t obase = (size_t)b * (32 * V_DIM * L_DIM) + (size_t)w0 * L_DIM;
#pragma unroll
  for (int o = 0; o < 32; ++o) {
    size_t base = obase + (size_t)o * (V_DIM * L_DIM);
    out[base + tid] = acc[0][o];
    out[base + tid + 256] = acc[1][o];
    out[base + tid + 512] = acc[2][o];
  }
}

// --------------------------- launcher ------------------------------------
extern "C" void kernel_launch(void* const* d_in, const int* in_sizes, int n_in,
                              void* d_out, int out_size, void* d_ws,
                              size_t ws_size, hipStream_t stream) {
  const float* x = (const float*)d_in[0];
  const float* A1 = (const float*)d_in[1];
  const float* A2 = (const float*)d_in[2];
  const float* nv1 = (const float*)d_in[3];
  const float* nv2 = (const float*)d_in[4];
  const float* W = (const float*)d_in[5];
  const float* bias = (const float*)d_in[6];
  float* out = (float*)d_out;

  char* ws = (char*)d_ws;
  // ws layout (bytes): R 301,989,888 | xT 50,331,648 | BtCat 12,582,912 |
  //                    As 6,291,456 | adp 4,194,304   => total ~375.4 MB
  __hip_bfloat16* R = (__hip_bfloat16*)(ws + 0);
  __hip_bfloat16* xT = (__hip_bfloat16*)(ws + 301989888ull);
  __hip_bfloat16* BtCat = (__hip_bfloat16*)(ws + 352321536ull);
  __hip_bfloat16* As = (__hip_bfloat16*)(ws + 364904448ull);
  float* adp = (float*)(ws + 371195904ull);

  // 1. adaptive adjacency
  adp_kernel<<<dim3(1024), dim3(128), 0, stream>>>(nv1, nv2, adp);
  // 2. bf16 casts: straight (As) + transposed (BtCat slices 0,2,4)
  cast_transpose<<<dim3(16, 16, 3), dim3(256), 0, stream>>>(A1, A2, adp, As, BtCat);
  // 3. squares: BtCat slice 2z+1 = (a^2)^T = At @ As^T   (M=N=K=1024)
  gemm_bt<0><<<dim3(8, 8, 3), dim3(256), 0, stream>>>(
      BtCat, As, BtCat + 1048576ull, 1024, 1024, 1024,
      2097152ll, 1048576ll, 2097152ll);
  // 4. x -> xT bf16
  transpose_x_k<<<dim3(2048), dim3(256), 0, stream>>>(x, xT);
  // 5. main diffusion GEMM: R = xT @ BtCat^T  (M=24576, N=6144, K=1024)
  gemm_bt<1><<<dim3(48, 192, 1), dim3(256), 0, stream>>>(
      xT, BtCat, R, 24576, 6144, 1024, 0ll, 0ll, 0ll);
  // 6. channel mix + bias -> out
  mix_kernel<<<dim3(16, 64), dim3(256), 0, stream>>>(R, xT, W, bias, out);
}